// Round 8
// baseline (48.654 us; speedup 1.0000x reference)
//
#include <hip/hip_runtime.h>

// DiceLoss: input [N=32, C=4, H=512, W=512] f32, target [N,1,H,W] i32.
// softmax over C; since softmax sums to 1, cardinality = 2*HW exactly, so
// loss = 1 - (2/(N*(2*HW+eps))) * sum_{all pixels} probs[target]
//      = 1 - sum_blocks (blocksum * SCALE),  SCALE = 2/(N*(2*HW+eps)).
//
// Structure history:
//  R3/R7 (33.5us): two dispatches, plain stores.  Main kernel ~28-29us =
//    ~94% of the 6.29 TB/s read-copy ceiling; the final-reduce dispatch is
//    the remaining ~4-5us.
//  R4/R6 (99us): single dispatch w/ ticket + __threadfence() -> ~125us of
//    per-block L2 writeback. Fences are the poison, not fusion itself.
//  This round: out[0] initialized to 1.0f via hipMemsetD32Async (4-byte
//    memset node), each block does ONE device-scope float atomicAdd of its
//    pre-scaled negative contribution. No fence, no second kernel. Atomic
//    order varies -> ~1e-6 jitter, threshold is 1.5e-2.

constexpr int N_   = 32;
constexpr int C_   = 4;
constexpr int HW_  = 512 * 512;                 // 2^18
constexpr float EPSF = 1e-6f;

constexpr int NBLK  = 2048;
constexpr int NTHR  = 256;
constexpr int TOTTH = NBLK * NTHR;              // 524288 threads
constexpr int NGROUPS = N_ * HW_ / 4;           // 2097152 float4-groups
constexpr int NITER = NGROUPS / TOTTH;          // exactly 4
static_assert(NITER * TOTTH == NGROUPS, "geometry must tile exactly");

// 2/(N*(2*HW+eps)) computed in double, truncated to float
constexpr float SCALE = (float)(2.0 / (32.0 * (2.0 * 262144.0 + 1e-6)));

__device__ __forceinline__ float px(float a, float b, float c, float d, int t) {
    float m  = fmaxf(fmaxf(a, b), fmaxf(c, d));
    float ea = __expf(a - m);
    float eb = __expf(b - m);
    float ec = __expf(c - m);
    float ed = __expf(d - m);
    float denom = (ea + eb) + (ec + ed);
    float et = (t == 0) ? ea : (t == 1) ? eb : (t == 2) ? ec : ed;
    return et * __builtin_amdgcn_rcpf(denom);   // ~1e-6 rel err, threshold 1.5e-2
}

__global__ __launch_bounds__(NTHR) void dice_partial(
        const float* __restrict__ x,
        const int*   __restrict__ tgt,
        float*       __restrict__ out) {
    const int tid = blockIdx.x * NTHR + threadIdx.x;
    float acc = 0.f;

    #pragma unroll
    for (int it = 0; it < NITER; ++it) {
        const int pix = (tid + it * TOTTH) << 2;   // 4 pixels per group
        const int n   = pix >> 18;                 // / HW_
        const int hw  = pix & (HW_ - 1);
        const float* base = x + (size_t)n * (C_ * HW_) + hw;

        float4 v0 = *reinterpret_cast<const float4*>(base);
        float4 v1 = *reinterpret_cast<const float4*>(base + HW_);
        float4 v2 = *reinterpret_cast<const float4*>(base + 2 * HW_);
        float4 v3 = *reinterpret_cast<const float4*>(base + 3 * HW_);
        int4   t4 = *reinterpret_cast<const int4*>(tgt + (size_t)n * HW_ + hw);

        acc += px(v0.x, v1.x, v2.x, v3.x, t4.x);
        acc += px(v0.y, v1.y, v2.y, v3.y, t4.y);
        acc += px(v0.z, v1.z, v2.z, v3.z, t4.z);
        acc += px(v0.w, v1.w, v2.w, v3.w, t4.w);
    }

    // wave (64-lane) reduce, fixed order
    #pragma unroll
    for (int off = 32; off > 0; off >>= 1)
        acc += __shfl_down(acc, off, 64);

    __shared__ float wsum[NTHR / 64];
    const int lane = threadIdx.x & 63;
    const int wid  = threadIdx.x >> 6;
    if (lane == 0) wsum[wid] = acc;
    __syncthreads();
    if (threadIdx.x == 0) {
        float bs = (wsum[0] + wsum[1]) + (wsum[2] + wsum[3]);
        atomicAdd(out, -bs * SCALE);   // device-scope, no fence needed
    }
}

extern "C" void kernel_launch(void* const* d_in, const int* in_sizes, int n_in,
                              void* d_out, int out_size, void* d_ws, size_t ws_size,
                              hipStream_t stream) {
    const float* x   = (const float*)d_in[0];
    const int*   tgt = (const int*)d_in[1];
    float*       out = (float*)d_out;

    // out[0] = 1.0f; blocks subtract their scaled contributions.
    hipMemsetD32Async(out, 0x3F800000u, 1, stream);
    dice_partial<<<NBLK, NTHR, 0, stream>>>(x, tgt, out);
}

// Round 9
// 44.988 us; speedup vs baseline: 1.0815x; 1.0815x over previous
//
#include <hip/hip_runtime.h>

// DiceLoss: input [N=32, C=4, H=512, W=512] f32, target [N,1,H,W] i32.
// softmax over C; since softmax sums to 1, cardinality = 2*HW exactly, so
// loss = 1 - (2/(N*(2*HW+eps))) * sum_{all pixels} probs[target].
//
// Structure ledger:
//  R3/R7 (33.5us): two dispatches, plain stores. k1 ~28-29us = ~94% of the
//    6.29 TB/s read ceiling; final dispatch+node = remaining ~4-5us.
//  R4/R6 (99us):  ticket + __threadfence() => per-block L2 writeback, fatal.
//  R8   (48.7us): 4B hipMemsetD32Async node => fill dispatches cost ~75us
//    REGARDLESS of size on this machine; never put fills in the graph.
//  R9: keep two plain-store dispatches. 1024 blocks x 8 iters (fewer block
//    launches, 1024 partials), and a minimal single-wave float4 final kernel
//    (no LDS, no __syncthreads).

constexpr int N_   = 32;
constexpr int C_   = 4;
constexpr int HW_  = 512 * 512;                 // 2^18
constexpr float EPSF = 1e-6f;

constexpr int NBLK  = 1024;
constexpr int NTHR  = 256;
constexpr int TOTTH = NBLK * NTHR;              // 262144 threads
constexpr int NGROUPS = N_ * HW_ / 4;           // 2097152 float4-groups
constexpr int NITER = NGROUPS / TOTTH;          // exactly 8
static_assert(NITER * TOTTH == NGROUPS, "geometry must tile exactly");

__device__ __forceinline__ float px(float a, float b, float c, float d, int t) {
    float m  = fmaxf(fmaxf(a, b), fmaxf(c, d));
    float ea = __expf(a - m);
    float eb = __expf(b - m);
    float ec = __expf(c - m);
    float ed = __expf(d - m);
    float denom = (ea + eb) + (ec + ed);
    float et = (t == 0) ? ea : (t == 1) ? eb : (t == 2) ? ec : ed;
    return et * __builtin_amdgcn_rcpf(denom);   // ~1e-6 rel err vs 1.5e-2 thr
}

__global__ __launch_bounds__(NTHR, 4) void dice_partial(
        const float* __restrict__ x,
        const int*   __restrict__ tgt,
        float*       __restrict__ partial) {
    const int tid = blockIdx.x * NTHR + threadIdx.x;
    float acc = 0.f;

    #pragma unroll
    for (int it = 0; it < NITER; ++it) {
        const int pix = (tid + it * TOTTH) << 2;   // 4 pixels per group
        const int n   = pix >> 18;                 // / HW_
        const int hw  = pix & (HW_ - 1);
        const float* base = x + (size_t)n * (C_ * HW_) + hw;

        float4 v0 = *reinterpret_cast<const float4*>(base);
        float4 v1 = *reinterpret_cast<const float4*>(base + HW_);
        float4 v2 = *reinterpret_cast<const float4*>(base + 2 * HW_);
        float4 v3 = *reinterpret_cast<const float4*>(base + 3 * HW_);
        int4   t4 = *reinterpret_cast<const int4*>(tgt + (size_t)n * HW_ + hw);

        acc += px(v0.x, v1.x, v2.x, v3.x, t4.x);
        acc += px(v0.y, v1.y, v2.y, v3.y, t4.y);
        acc += px(v0.z, v1.z, v2.z, v3.z, t4.z);
        acc += px(v0.w, v1.w, v2.w, v3.w, t4.w);
    }

    // wave (64-lane) reduce, fixed order -> deterministic
    #pragma unroll
    for (int off = 32; off > 0; off >>= 1)
        acc += __shfl_down(acc, off, 64);

    __shared__ float wsum[NTHR / 64];
    const int lane = threadIdx.x & 63;
    const int wid  = threadIdx.x >> 6;
    if (lane == 0) wsum[wid] = acc;
    __syncthreads();
    if (threadIdx.x == 0)
        partial[blockIdx.x] = (wsum[0] + wsum[1]) + (wsum[2] + wsum[3]);
}

// single wave, float4 loads, no LDS / no syncthreads
__global__ __launch_bounds__(64) void dice_final(
        const float* __restrict__ partial, float* __restrict__ out) {
    const int lane = threadIdx.x;                  // 0..63
    const float4* p4 = reinterpret_cast<const float4*>(partial);
    float acc = 0.f;
    #pragma unroll
    for (int r = 0; r < NBLK / (64 * 4); ++r) {    // 4 float4 per lane
        float4 v = p4[lane + r * 64];
        acc += (v.x + v.y) + (v.z + v.w);
    }
    #pragma unroll
    for (int off = 32; off > 0; off >>= 1)
        acc += __shfl_down(acc, off, 64);
    if (lane == 0) {
        float card = 2.0f * (float)HW_ + EPSF;
        out[0] = 1.0f - 2.0f * acc / ((float)N_ * card);
    }
}

extern "C" void kernel_launch(void* const* d_in, const int* in_sizes, int n_in,
                              void* d_out, int out_size, void* d_ws, size_t ws_size,
                              hipStream_t stream) {
    const float* x   = (const float*)d_in[0];
    const int*   tgt = (const int*)d_in[1];
    float*       out = (float*)d_out;
    float*       par = (float*)d_ws;

    dice_partial<<<NBLK, NTHR, 0, stream>>>(x, tgt, par);
    dice_final<<<1, 64, 0, stream>>>(par, out);
}

// Round 10
// 33.487 us; speedup vs baseline: 1.4529x; 1.3434x over previous
//
#include <hip/hip_runtime.h>

// DiceLoss: input [N=32, C=4, H=512, W=512] f32, target [N,1,H,W] i32.
// softmax over C; since softmax sums to 1, cardinality = 2*HW exactly, so
// loss = 1 - (2/(N*(2*HW+eps))) * sum_{all pixels} probs[target].
//
// Structure ledger (what's proven):
//  R3/R7 (33.5us): two dispatches, plain stores. k1 = 2048blk x 256thr x
//    4 iters, VGPR=48, no spills, ~28.5us ≈ 94% of 6.29 TB/s read ceiling.
//  R4/R6 (99us):  ticket + __threadfence() => per-block L2 writeback. FATAL.
//  R8   (48.7us): 4B hipMemsetD32Async node => fill dispatch ~75us
//    regardless of size. FATAL. No fill/memset nodes in the graph.
//  R9   (45.0us): NITER=8 + __launch_bounds__(256,4) => VGPR cap 64 =>
//    39 MB scratch spill traffic, k1 77us. FATAL. Don't cap registers,
//    don't over-unroll.
//  R10: k1 reverted to R7 exactly; final = single wave, float4, no LDS.

constexpr int N_   = 32;
constexpr int C_   = 4;
constexpr int HW_  = 512 * 512;                 // 2^18
constexpr float EPSF = 1e-6f;

constexpr int NBLK  = 2048;
constexpr int NTHR  = 256;
constexpr int TOTTH = NBLK * NTHR;              // 524288 threads
constexpr int NGROUPS = N_ * HW_ / 4;           // 2097152 float4-groups
constexpr int NITER = NGROUPS / TOTTH;          // exactly 4
static_assert(NITER * TOTTH == NGROUPS, "geometry must tile exactly");

__device__ __forceinline__ float px(float a, float b, float c, float d, int t) {
    float m  = fmaxf(fmaxf(a, b), fmaxf(c, d));
    float ea = __expf(a - m);
    float eb = __expf(b - m);
    float ec = __expf(c - m);
    float ed = __expf(d - m);
    float denom = (ea + eb) + (ec + ed);
    float et = (t == 0) ? ea : (t == 1) ? eb : (t == 2) ? ec : ed;
    return et * __builtin_amdgcn_rcpf(denom);   // ~1e-6 rel err vs 1.5e-2 thr
}

__global__ __launch_bounds__(NTHR) void dice_partial(
        const float* __restrict__ x,
        const int*   __restrict__ tgt,
        float*       __restrict__ partial) {
    const int tid = blockIdx.x * NTHR + threadIdx.x;
    float acc = 0.f;

    #pragma unroll
    for (int it = 0; it < NITER; ++it) {
        const int pix = (tid + it * TOTTH) << 2;   // 4 pixels per group
        const int n   = pix >> 18;                 // / HW_
        const int hw  = pix & (HW_ - 1);
        const float* base = x + (size_t)n * (C_ * HW_) + hw;

        float4 v0 = *reinterpret_cast<const float4*>(base);
        float4 v1 = *reinterpret_cast<const float4*>(base + HW_);
        float4 v2 = *reinterpret_cast<const float4*>(base + 2 * HW_);
        float4 v3 = *reinterpret_cast<const float4*>(base + 3 * HW_);
        int4   t4 = *reinterpret_cast<const int4*>(tgt + (size_t)n * HW_ + hw);

        acc += px(v0.x, v1.x, v2.x, v3.x, t4.x);
        acc += px(v0.y, v1.y, v2.y, v3.y, t4.y);
        acc += px(v0.z, v1.z, v2.z, v3.z, t4.z);
        acc += px(v0.w, v1.w, v2.w, v3.w, t4.w);
    }

    // wave (64-lane) reduce, fixed order -> deterministic
    #pragma unroll
    for (int off = 32; off > 0; off >>= 1)
        acc += __shfl_down(acc, off, 64);

    __shared__ float wsum[NTHR / 64];
    const int lane = threadIdx.x & 63;
    const int wid  = threadIdx.x >> 6;
    if (lane == 0) wsum[wid] = acc;
    __syncthreads();
    if (threadIdx.x == 0)
        partial[blockIdx.x] = (wsum[0] + wsum[1]) + (wsum[2] + wsum[3]);
}

// single wave, float4 loads, no LDS / no __syncthreads
__global__ __launch_bounds__(64) void dice_final(
        const float* __restrict__ partial, float* __restrict__ out) {
    const int lane = threadIdx.x;                  // 0..63
    const float4* p4 = reinterpret_cast<const float4*>(partial);
    float acc = 0.f;
    #pragma unroll
    for (int r = 0; r < NBLK / (64 * 4); ++r) {    // 8 float4 per lane
        float4 v = p4[lane + r * 64];
        acc += (v.x + v.y) + (v.z + v.w);
    }
    #pragma unroll
    for (int off = 32; off > 0; off >>= 1)
        acc += __shfl_down(acc, off, 64);
    if (lane == 0) {
        float card = 2.0f * (float)HW_ + EPSF;
        out[0] = 1.0f - 2.0f * acc / ((float)N_ * card);
    }
}

extern "C" void kernel_launch(void* const* d_in, const int* in_sizes, int n_in,
                              void* d_out, int out_size, void* d_ws, size_t ws_size,
                              hipStream_t stream) {
    const float* x   = (const float*)d_in[0];
    const int*   tgt = (const int*)d_in[1];
    float*       out = (float*)d_out;
    float*       par = (float*)d_ws;

    dice_partial<<<NBLK, NTHR, 0, stream>>>(x, tgt, par);
    dice_final<<<1, 64, 0, stream>>>(par, out);
}